// Round 4
// baseline (735.400 us; speedup 1.0000x reference)
//
#include <hip/hip_runtime.h>
#include <math.h>

#define F 128
#define THREEF 384
#define N_RBF 20
#define CUTOFF 5.0f
#define CAP 64
#define TLDS_STRIDE 136   // shorts; 272 B row: 16B-aligned, ~2-way banks (free)

typedef __bf16 bf16x8 __attribute__((ext_vector_type(8)));
typedef float  f32x4  __attribute__((ext_vector_type(4)));

// ---------------------------------------------------------------------------
// Prep (fused, block-range sliced):
//   blocks [0, EB)        : build — CSR slot via atomic, pack written directly
//                           at (dst,slot) so gather reads contiguously
//   blocks [EB, EB+256)   : wcast — W1,W2 -> bf16 k-major
//   blocks [EB+256, +8)   : wrt — chunked transpose of Wr for gather
// pack row = {s1, 2cos(x), fcut, ux, uy, uz, src_bits, 0}
// ---------------------------------------------------------------------------
__global__ __launch_bounds__(256) void prep_kernel(
    const float* __restrict__ d_ij, const float* __restrict__ unit_r,
    const int* __restrict__ nbrs,
    const float* __restrict__ W1, const float* __restrict__ W2,
    const float* __restrict__ Wr,
    int* __restrict__ cnt, float* __restrict__ pack,
    __bf16* __restrict__ W1T, __bf16* __restrict__ W2T,
    float* __restrict__ WrT, int E, int EB)
{
    const int tid = threadIdx.x;
    const int b   = blockIdx.x;

    if (b < EB) {                       // ---- build
        const int e = b * 256 + tid;
        if (e >= E) return;
        const int2 nb = ((const int2*)nbrs)[e];
        const int dst = nb.x;
        const int src = nb.y;
        const int slot = atomicAdd(&cnt[dst], 1);
        if (slot >= CAP) return;

        const float d = d_ij[e];
        const float x = (float)M_PI * d * (1.0f / CUTOFF);
        float sx, cx;
        __sincosf(x, &sx, &cx);
        const float fcut = (d < CUTOFF) ? 0.5f * (cx + 1.0f) : 0.0f;
        float4 q0, q1;
        q0.x = sx * fcut / d;           // rbff_1; recurrence keeps fcut/d scale
        q0.y = 2.0f * cx;
        q0.z = fcut;
        q0.w = unit_r[3 * e + 0];
        q1.x = unit_r[3 * e + 1];
        q1.y = unit_r[3 * e + 2];
        q1.z = __int_as_float(src);
        q1.w = 0.0f;
        float4* pk = (float4*)(pack + ((size_t)dst * CAP + slot) * 8);
        pk[0] = q0;
        pk[1] = q1;
    } else if (b < EB + 256) {          // ---- wcast
        const int idx = (b - EB) * 256 + tid;
        if (idx < 128 * 128) {
            const int n = idx >> 7, k = idx & 127;
            W1T[idx] = (__bf16)W1[k * F + n];
        }
        if (idx < 384 * 128) {
            const int n = idx >> 7, k = idx & 127;
            W2T[idx] = (__bf16)W2[k * THREEF + n];
        }
    } else {                            // ---- wrt
        const int idx = (b - EB - 256) * 256 + tid;   // 0..1919
        if (idx >= 5 * 3 * 128) return;
        const int f  = idx & 127;
        const int c  = (idx >> 7) % 3;
        const int n4 = idx / (3 * 128);
        float4 v;
        v.x = Wr[(4 * n4 + 0) * THREEF + c * 128 + f];
        v.y = Wr[(4 * n4 + 1) * THREEF + c * 128 + f];
        v.z = Wr[(4 * n4 + 2) * THREEF + c * 128 + f];
        v.w = Wr[(4 * n4 + 3) * THREEF + c * 128 + f];
        ((float4*)WrT)[idx] = v;
    }
}

// ---------------------------------------------------------------------------
// MLP via bf16 MFMA (fp32 accumulate): phi = silu(h@W1+b1)@W2 + b2.
// phi stored INTERLEAVED as (N,128) float4 {c0,c1,c2,pad} so the gather
// reads one dwordx4 per edge instead of 3 scattered dwords.
// ---------------------------------------------------------------------------
__global__ __launch_bounds__(256) void mlp_mfma_kernel(
    const float* __restrict__ h,      // (N,128) fp32
    const __bf16* __restrict__ W1T,   // (128n,128k)
    const float* __restrict__ b1,     // (128)
    const __bf16* __restrict__ W2T,   // (384n,128k)
    const float* __restrict__ b2,     // (384)
    float* __restrict__ phi, int N)   // (N,128,4) interleaved
{
    __shared__ __bf16 t_lds[4][16 * TLDS_STRIDE];

    const int wave = threadIdx.x >> 6;
    const int lane = threadIdx.x & 63;
    const int m    = lane & 15;
    const int quad = lane >> 4;
    const int node0 = blockIdx.x * 64 + wave * 16;
    if (node0 >= N) return;

    bf16x8 a1[4];
    #pragma unroll
    for (int kb = 0; kb < 4; ++kb) {
        const float* hp = h + (size_t)(node0 + m) * F + kb * 32 + quad * 8;
        const float4 x0 = *(const float4*)hp;
        const float4 x1 = *(const float4*)(hp + 4);
        bf16x8 a;
        a[0] = (__bf16)x0.x; a[1] = (__bf16)x0.y;
        a[2] = (__bf16)x0.z; a[3] = (__bf16)x0.w;
        a[4] = (__bf16)x1.x; a[5] = (__bf16)x1.y;
        a[6] = (__bf16)x1.z; a[7] = (__bf16)x1.w;
        a1[kb] = a;
    }

    #pragma unroll
    for (int ct = 0; ct < 8; ++ct) {
        f32x4 acc = {0.0f, 0.0f, 0.0f, 0.0f};
        #pragma unroll
        for (int kb = 0; kb < 4; ++kb) {
            const bf16x8 b =
                *(const bf16x8*)(W1T + (size_t)(ct * 16 + m) * F + kb * 32 + quad * 8);
            acc = __builtin_amdgcn_mfma_f32_16x16x32_bf16(a1[kb], b, acc, 0, 0, 0);
        }
        const int col = ct * 16 + m;
        const float bb = b1[col];
        #pragma unroll
        for (int reg = 0; reg < 4; ++reg) {
            const float x = acc[reg] + bb;
            const float s = x / (1.0f + __expf(-x));
            t_lds[wave][(quad * 4 + reg) * TLDS_STRIDE + col] = (__bf16)s;
        }
    }

    bf16x8 a2[4];
    #pragma unroll
    for (int kb = 0; kb < 4; ++kb)
        a2[kb] = *(const bf16x8*)&t_lds[wave][m * TLDS_STRIDE + kb * 32 + quad * 8];

    #pragma unroll
    for (int ct = 0; ct < 24; ++ct) {
        f32x4 acc = {0.0f, 0.0f, 0.0f, 0.0f};
        #pragma unroll
        for (int kb = 0; kb < 4; ++kb) {
            const bf16x8 b =
                *(const bf16x8*)(W2T + (size_t)(ct * 16 + m) * F + kb * 32 + quad * 8);
            acc = __builtin_amdgcn_mfma_f32_16x16x32_bf16(a2[kb], b, acc, 0, 0, 0);
        }
        const int col   = ct * 16 + m;
        const int plane = col >> 7;
        const int fc    = col & 127;
        const float bb  = b2[col];
        #pragma unroll
        for (int reg = 0; reg < 4; ++reg) {
            const int row = quad * 4 + reg;
            phi[((((size_t)(node0 + row)) * F + fc) << 2) + plane] = acc[reg] + bb;
        }
    }
}

// ---------------------------------------------------------------------------
// Gather: 256 threads = 2 nodes/block. R4: R1 structure (4 KB LDS, occ-safe)
// + 4-edge blocking.
//  - WrT reads stay VMEM (L1-resident, 30 KB): 15 dwordx4 per 4-edge body
//    instead of per edge (4x amortization). Each w triple is live only
//    inside its n4 iteration (j-loop is INSIDE), so ~12 w-VGPRs live —
//    compiler cannot un-amortize, and no pin/spill is needed.
//  - 4 independent recurrence chains interleave (ILP) instead of one
//    serial 20-deep chain.
//  - 16 gather loads (phi4, v_i) issued at body start, consumed after
//    ~256 FMA -> within-body latency cover.
//  - Tail: pack rows zero-padded to multiple of 4; s1=twoc=fcut=0 makes the
//    pad contribution exactly 0, src=0 is a safe (discarded) gather address.
// ---------------------------------------------------------------------------
__global__ __launch_bounds__(256, 4) void gather_kernel(
    const float4* __restrict__ phi4,     // (N,128) quads {c0,c1,c2,pad}
    const float* __restrict__ v_i,       // (N,128,3)
    const float* __restrict__ WrT,       // (15,128) float4 chunked transpose
    const float* __restrict__ br,        // (384)
    const int*   __restrict__ cnt,       // (N)
    const float* __restrict__ pack,      // (N,CAP,8)
    float* __restrict__ dh,              // (N,128)
    float* __restrict__ dv,              // (N,128,3)
    int N)
{
    __shared__ float4 s_pack[2][CAP * 2];   // 4 KB

    const int tid  = threadIdx.x;
    const int half = tid >> 7;
    const int f    = tid & 127;
    const int node = blockIdx.x * 2 + half;

    const int deg0 = cnt[node];
    const int deg  = deg0 < CAP ? deg0 : CAP;
    const int degR = (deg + 3) & ~3;         // pad to 4-edge blocks (<= CAP)

    {   // stage this node's pack rows; zero the pad slots
        const float4* srcp = (const float4*)(pack + (size_t)node * CAP * 8);
        if (f < 2 * degR) {
            float4 v = make_float4(0.0f, 0.0f, 0.0f, 0.0f);
            if (f < 2 * deg) v = srcp[f];
            s_pack[half][f] = v;
        }
    }
    __syncthreads();

    const float br0 = br[f], br1 = br[f + 128], br2 = br[f + 256];
    const float4* wTg = (const float4*)WrT;   // wTg[(n4*3 + c)*128 + f]

    float dh_acc = 0.0f, dv0 = 0.0f, dv1 = 0.0f, dv2 = 0.0f;

    for (int i0 = 0; i0 < degR; i0 += 4) {
        float s1[4], twoc[4], fcut[4], ux[4], uy[4], uz[4];
        int   srcn[4];
        #pragma unroll
        for (int j = 0; j < 4; ++j) {
            const float* q = (const float*)&s_pack[half][2 * (i0 + j)];
            s1[j] = q[0]; twoc[j] = q[1]; fcut[j] = q[2];
            ux[j] = q[3]; uy[j]   = q[4]; uz[j]   = q[5];
            srcn[j] = __builtin_amdgcn_readfirstlane(__float_as_int(q[6]));
        }

        // issue all 16 gather loads up front; consumed after the FMA block
        float4 ph[4];
        float  vx[4], vy[4], vz[4];
        #pragma unroll
        for (int j = 0; j < 4; ++j) {
            ph[j] = phi4[(size_t)srcn[j] * F + f];
            const float* vs = v_i + (size_t)srcn[j] * THREEF + 3 * f;
            vx[j] = vs[0]; vy[j] = vs[1]; vz[j] = vs[2];
        }

        float a0[4], a1[4], a2[4], rp[4], rc[4];
        #pragma unroll
        for (int j = 0; j < 4; ++j) {
            a0[j] = br0 * fcut[j];
            a1[j] = br1 * fcut[j];
            a2[j] = br2 * fcut[j];
            rp[j] = 0.0f; rc[j] = s1[j];
        }

        #pragma unroll
        for (int n4 = 0; n4 < 5; ++n4) {
            const float4 w0 = wTg[(n4 * 3 + 0) * 128 + f];
            const float4 w1 = wTg[(n4 * 3 + 1) * 128 + f];
            const float4 w2 = wTg[(n4 * 3 + 2) * 128 + f];
            #pragma unroll
            for (int k = 0; k < 4; ++k) {
                const float wa = ((const float*)&w0)[k];
                const float wb = ((const float*)&w1)[k];
                const float wc = ((const float*)&w2)[k];
                #pragma unroll
                for (int j = 0; j < 4; ++j) {
                    a0[j] = fmaf(rc[j], wa, a0[j]);
                    a1[j] = fmaf(rc[j], wb, a1[j]);
                    a2[j] = fmaf(rc[j], wc, a2[j]);
                    const float rn = fmaf(twoc[j], rc[j], -rp[j]);
                    rp[j] = rc[j]; rc[j] = rn;
                }
            }
        }

        #pragma unroll
        for (int j = 0; j < 4; ++j) {
            const float f1 = ph[j].x * a0[j];
            const float f2 = ph[j].y * a1[j];
            const float f3 = ph[j].z * a2[j];
            dh_acc += f3;
            dv0 = fmaf(f1, ux[j], fmaf(f2, vx[j], dv0));
            dv1 = fmaf(f1, uy[j], fmaf(f2, vy[j], dv1));
            dv2 = fmaf(f1, uz[j], fmaf(f2, vz[j], dv2));
        }
    }

    dh[(size_t)node * F + f] = dh_acc;
    float* dvp = dv + (size_t)node * THREEF + 3 * f;
    dvp[0] = dv0;
    dvp[1] = dv1;
    dvp[2] = dv2;
}

extern "C" void kernel_launch(void* const* d_in, const int* in_sizes, int n_in,
                              void* d_out, int out_size, void* d_ws, size_t ws_size,
                              hipStream_t stream) {
    const float* h_i    = (const float*)d_in[0];
    const float* v_i    = (const float*)d_in[1];
    const float* d_ij   = (const float*)d_in[2];
    const float* unit_r = (const float*)d_in[3];
    const int*   nbrs   = (const int*)  d_in[4];
    const float* W1     = (const float*)d_in[5];
    const float* b1     = (const float*)d_in[6];
    const float* W2     = (const float*)d_in[7];
    const float* b2     = (const float*)d_in[8];
    const float* Wr     = (const float*)d_in[9];
    const float* br     = (const float*)d_in[10];

    const int N = in_sizes[0] / F;       // 20000
    const int E = in_sizes[2];           // 320000

    float* dh = (float*)d_out;              // (N,128)
    float* dv = dh + (size_t)N * F;         // (N,128,3)

    // workspace: phi4 (4NF, interleaved) | pack (N*CAP*8) | WrT | cnt | W1T | W2T
    float*  phi  = (float*)d_ws;                           // 41 MB
    float*  pack = phi + (size_t)4 * N * F;                // 41 MB
    float*  WrT  = pack + (size_t)N * CAP * 8;             // 30 KB
    int*    cnt  = (int*)(WrT + 5 * 3 * 128 * 4);          // 80 KB
    __bf16* W1T  = (__bf16*)(cnt + N);                     // 32 KB
    __bf16* W2T  = W1T + 128 * 128;                        // 96 KB

    const int EB = (E + 255) / 256;      // 1250 build blocks

    hipMemsetAsync(cnt, 0, (size_t)N * sizeof(int), stream);

    prep_kernel<<<EB + 256 + 8, 256, 0, stream>>>(
        d_ij, unit_r, nbrs, W1, W2, Wr, cnt, pack, W1T, W2T, WrT, E, EB);
    mlp_mfma_kernel<<<(N + 63) / 64, 256, 0, stream>>>(h_i, W1T, b1, W2T, b2,
                                                       phi, N);
    gather_kernel<<<N / 2, 256, 0, stream>>>((const float4*)phi, v_i, WrT, br,
                                             cnt, pack, dh, dv, N);
}

// Round 5
// 326.651 us; speedup vs baseline: 2.2513x; 2.2513x over previous
//
#include <hip/hip_runtime.h>
#include <math.h>

#define F 128
#define THREEF 384
#define N_RBF 20
#define CUTOFF 5.0f
#define CAP 64
#define TLDS_STRIDE 136   // shorts; 272 B row: 16B-aligned, ~2-way banks (free)

typedef __bf16 bf16x8 __attribute__((ext_vector_type(8)));
typedef float  f32x4  __attribute__((ext_vector_type(4)));

// ---------------------------------------------------------------------------
// Prep (fused, block-range sliced):
//   blocks [0, EB)        : build — CSR slot via atomic, pack written directly
//                           at (dst,slot) so gather reads contiguously
//   blocks [EB, EB+256)   : wcast — W1,W2 -> bf16 k-major
//   blocks [EB+256, +8)   : wrt — chunked transpose of Wr for gather
// pack row = {s1, 2cos(x), fcut, ux, uy, uz, src_bits, 0}
// ---------------------------------------------------------------------------
__global__ __launch_bounds__(256) void prep_kernel(
    const float* __restrict__ d_ij, const float* __restrict__ unit_r,
    const int* __restrict__ nbrs,
    const float* __restrict__ W1, const float* __restrict__ W2,
    const float* __restrict__ Wr,
    int* __restrict__ cnt, float* __restrict__ pack,
    __bf16* __restrict__ W1T, __bf16* __restrict__ W2T,
    float* __restrict__ WrT, int E, int EB)
{
    const int tid = threadIdx.x;
    const int b   = blockIdx.x;

    if (b < EB) {                       // ---- build
        const int e = b * 256 + tid;
        if (e >= E) return;
        const int2 nb = ((const int2*)nbrs)[e];
        const int dst = nb.x;
        const int src = nb.y;
        const int slot = atomicAdd(&cnt[dst], 1);
        if (slot >= CAP) return;

        const float d = d_ij[e];
        const float x = (float)M_PI * d * (1.0f / CUTOFF);
        float sx, cx;
        __sincosf(x, &sx, &cx);
        const float fcut = (d < CUTOFF) ? 0.5f * (cx + 1.0f) : 0.0f;
        float4 q0, q1;
        q0.x = sx * fcut / d;           // rbff_1; recurrence keeps fcut/d scale
        q0.y = 2.0f * cx;
        q0.z = fcut;
        q0.w = unit_r[3 * e + 0];
        q1.x = unit_r[3 * e + 1];
        q1.y = unit_r[3 * e + 2];
        q1.z = __int_as_float(src);
        q1.w = 0.0f;
        float4* pk = (float4*)(pack + ((size_t)dst * CAP + slot) * 8);
        pk[0] = q0;
        pk[1] = q1;
    } else if (b < EB + 256) {          // ---- wcast
        const int idx = (b - EB) * 256 + tid;
        if (idx < 128 * 128) {
            const int n = idx >> 7, k = idx & 127;
            W1T[idx] = (__bf16)W1[k * F + n];
        }
        if (idx < 384 * 128) {
            const int n = idx >> 7, k = idx & 127;
            W2T[idx] = (__bf16)W2[k * THREEF + n];
        }
    } else {                            // ---- wrt
        const int idx = (b - EB - 256) * 256 + tid;   // 0..1919
        if (idx >= 5 * 3 * 128) return;
        const int f  = idx & 127;
        const int c  = (idx >> 7) % 3;
        const int n4 = idx / (3 * 128);
        float4 v;
        v.x = Wr[(4 * n4 + 0) * THREEF + c * 128 + f];
        v.y = Wr[(4 * n4 + 1) * THREEF + c * 128 + f];
        v.z = Wr[(4 * n4 + 2) * THREEF + c * 128 + f];
        v.w = Wr[(4 * n4 + 3) * THREEF + c * 128 + f];
        ((float4*)WrT)[idx] = v;
    }
}

// ---------------------------------------------------------------------------
// MLP via bf16 MFMA (fp32 accumulate): phi = silu(h@W1+b1)@W2 + b2.
// phi stored INTERLEAVED as (N,128) float4 {c0,c1,c2,pad} so the gather
// reads one dwordx4 per edge instead of 3 scattered dwords.
// ---------------------------------------------------------------------------
__global__ __launch_bounds__(256) void mlp_mfma_kernel(
    const float* __restrict__ h,      // (N,128) fp32
    const __bf16* __restrict__ W1T,   // (128n,128k)
    const float* __restrict__ b1,     // (128)
    const __bf16* __restrict__ W2T,   // (384n,128k)
    const float* __restrict__ b2,     // (384)
    float* __restrict__ phi, int N)   // (N,128,4) interleaved
{
    __shared__ __bf16 t_lds[4][16 * TLDS_STRIDE];

    const int wave = threadIdx.x >> 6;
    const int lane = threadIdx.x & 63;
    const int m    = lane & 15;
    const int quad = lane >> 4;
    const int node0 = blockIdx.x * 64 + wave * 16;
    if (node0 >= N) return;

    bf16x8 a1[4];
    #pragma unroll
    for (int kb = 0; kb < 4; ++kb) {
        const float* hp = h + (size_t)(node0 + m) * F + kb * 32 + quad * 8;
        const float4 x0 = *(const float4*)hp;
        const float4 x1 = *(const float4*)(hp + 4);
        bf16x8 a;
        a[0] = (__bf16)x0.x; a[1] = (__bf16)x0.y;
        a[2] = (__bf16)x0.z; a[3] = (__bf16)x0.w;
        a[4] = (__bf16)x1.x; a[5] = (__bf16)x1.y;
        a[6] = (__bf16)x1.z; a[7] = (__bf16)x1.w;
        a1[kb] = a;
    }

    #pragma unroll
    for (int ct = 0; ct < 8; ++ct) {
        f32x4 acc = {0.0f, 0.0f, 0.0f, 0.0f};
        #pragma unroll
        for (int kb = 0; kb < 4; ++kb) {
            const bf16x8 b =
                *(const bf16x8*)(W1T + (size_t)(ct * 16 + m) * F + kb * 32 + quad * 8);
            acc = __builtin_amdgcn_mfma_f32_16x16x32_bf16(a1[kb], b, acc, 0, 0, 0);
        }
        const int col = ct * 16 + m;
        const float bb = b1[col];
        #pragma unroll
        for (int reg = 0; reg < 4; ++reg) {
            const float x = acc[reg] + bb;
            const float s = x / (1.0f + __expf(-x));
            t_lds[wave][(quad * 4 + reg) * TLDS_STRIDE + col] = (__bf16)s;
        }
    }

    bf16x8 a2[4];
    #pragma unroll
    for (int kb = 0; kb < 4; ++kb)
        a2[kb] = *(const bf16x8*)&t_lds[wave][m * TLDS_STRIDE + kb * 32 + quad * 8];

    #pragma unroll
    for (int ct = 0; ct < 24; ++ct) {
        f32x4 acc = {0.0f, 0.0f, 0.0f, 0.0f};
        #pragma unroll
        for (int kb = 0; kb < 4; ++kb) {
            const bf16x8 b =
                *(const bf16x8*)(W2T + (size_t)(ct * 16 + m) * F + kb * 32 + quad * 8);
            acc = __builtin_amdgcn_mfma_f32_16x16x32_bf16(a2[kb], b, acc, 0, 0, 0);
        }
        const int col   = ct * 16 + m;
        const int plane = col >> 7;
        const int fc    = col & 127;
        const float bb  = b2[col];
        #pragma unroll
        for (int reg = 0; reg < 4; ++reg) {
            const int row = quad * 4 + reg;
            phi[((((size_t)(node0 + row)) * F + fc) << 2) + plane] = acc[reg] + bb;
        }
    }
}

// ---------------------------------------------------------------------------
// Gather: 256 threads = 2 nodes/block. R5: R1 structure (4 KB LDS, occ 37%,
// VALU 79% verified) + TWO-edge blocking with NAMED scalars.
// R4 post-mortem: the backend pins this kernel at the 64-VGPR granule and
// spills anything bigger (754 MB scratch writes at 4-edge blocking). Two
// chains of named scalars peak at ~60 live VGPRs -> fits, no spill.
//  - WrT reads stay VMEM (L1-resident): 15 dwordx4 per 2 edges (2x amortize),
//    loads live inside the n4 loop serving both chains (duplication would
//    cost VMEM, so the compiler keeps them shared).
//  - phi read: one dwordx4 from interleaved (N,128,4).
//  - 2 independent recurrence chains give ILP on the 20-deep serial chain.
//  - Tail: pack rows zero-padded to even; s1=twoc=fcut=0 => contribution 0,
//    src=0 is a safe (discarded) gather address.
// ---------------------------------------------------------------------------
__global__ __launch_bounds__(256, 4) void gather_kernel(
    const float4* __restrict__ phi4,     // (N,128) quads {c0,c1,c2,pad}
    const float* __restrict__ v_i,       // (N,128,3)
    const float* __restrict__ WrT,       // (15,128) float4 chunked transpose
    const float* __restrict__ br,        // (384)
    const int*   __restrict__ cnt,       // (N)
    const float* __restrict__ pack,      // (N,CAP,8)
    float* __restrict__ dh,              // (N,128)
    float* __restrict__ dv,              // (N,128,3)
    int N)
{
    __shared__ float4 s_pack[2][CAP * 2];   // 4 KB

    const int tid  = threadIdx.x;
    const int half = tid >> 7;
    const int f    = tid & 127;
    const int node = blockIdx.x * 2 + half;

    const int deg0 = cnt[node];
    const int deg  = deg0 < CAP ? deg0 : CAP;
    const int degR = (deg + 1) & ~1;         // pad to 2-edge blocks (<= CAP)

    {   // stage this node's pack rows; zero the pad slot
        const float4* srcp = (const float4*)(pack + (size_t)node * CAP * 8);
        if (f < 2 * degR) {
            float4 v = make_float4(0.0f, 0.0f, 0.0f, 0.0f);
            if (f < 2 * deg) v = srcp[f];
            s_pack[half][f] = v;
        }
    }
    __syncthreads();

    const float br0 = br[f], br1 = br[f + 128], br2 = br[f + 256];
    const float4* wTg = (const float4*)WrT;   // wTg[(n4*3 + c)*128 + f]

    float dh_acc = 0.0f, dv0 = 0.0f, dv1 = 0.0f, dv2 = 0.0f;

    for (int i0 = 0; i0 < degR; i0 += 2) {
        const float* qA = (const float*)&s_pack[half][2 * i0];
        const float* qB = (const float*)&s_pack[half][2 * i0 + 2];

        const float s1A = qA[0], twocA = qA[1], fcutA = qA[2];
        const float uxA = qA[3], uyA = qA[4], uzA = qA[5];
        const int srcA = __builtin_amdgcn_readfirstlane(__float_as_int(qA[6]));
        const float s1B = qB[0], twocB = qB[1], fcutB = qB[2];
        const float uxB = qB[3], uyB = qB[4], uzB = qB[5];
        const int srcB = __builtin_amdgcn_readfirstlane(__float_as_int(qB[6]));

        // gather loads issued up front, consumed after the FMA block
        const float4 phA = phi4[(size_t)srcA * F + f];
        const float* vsA = v_i + (size_t)srcA * THREEF + 3 * f;
        const float vxA = vsA[0], vyA = vsA[1], vzA = vsA[2];
        const float4 phB = phi4[(size_t)srcB * F + f];
        const float* vsB = v_i + (size_t)srcB * THREEF + 3 * f;
        const float vxB = vsB[0], vyB = vsB[1], vzB = vsB[2];

        float a0A = br0 * fcutA, a1A = br1 * fcutA, a2A = br2 * fcutA;
        float a0B = br0 * fcutB, a1B = br1 * fcutB, a2B = br2 * fcutB;
        float rpA = 0.0f, rcA = s1A;
        float rpB = 0.0f, rcB = s1B;

        #pragma unroll
        for (int n4 = 0; n4 < 5; ++n4) {
            const float4 w0 = wTg[(n4 * 3 + 0) * 128 + f];
            const float4 w1 = wTg[(n4 * 3 + 1) * 128 + f];
            const float4 w2 = wTg[(n4 * 3 + 2) * 128 + f];
            #pragma unroll
            for (int k = 0; k < 4; ++k) {
                const float wa = ((const float*)&w0)[k];
                const float wb = ((const float*)&w1)[k];
                const float wc = ((const float*)&w2)[k];
                a0A = fmaf(rcA, wa, a0A);
                a1A = fmaf(rcA, wb, a1A);
                a2A = fmaf(rcA, wc, a2A);
                const float rnA = fmaf(twocA, rcA, -rpA);
                rpA = rcA; rcA = rnA;
                a0B = fmaf(rcB, wa, a0B);
                a1B = fmaf(rcB, wb, a1B);
                a2B = fmaf(rcB, wc, a2B);
                const float rnB = fmaf(twocB, rcB, -rpB);
                rpB = rcB; rcB = rnB;
            }
        }

        const float f1A = phA.x * a0A;
        const float f2A = phA.y * a1A;
        const float f3A = phA.z * a2A;
        dh_acc += f3A;
        dv0 = fmaf(f1A, uxA, fmaf(f2A, vxA, dv0));
        dv1 = fmaf(f1A, uyA, fmaf(f2A, vyA, dv1));
        dv2 = fmaf(f1A, uzA, fmaf(f2A, vzA, dv2));

        const float f1B = phB.x * a0B;
        const float f2B = phB.y * a1B;
        const float f3B = phB.z * a2B;
        dh_acc += f3B;
        dv0 = fmaf(f1B, uxB, fmaf(f2B, vxB, dv0));
        dv1 = fmaf(f1B, uyB, fmaf(f2B, vyB, dv1));
        dv2 = fmaf(f1B, uzB, fmaf(f2B, vzB, dv2));
    }

    dh[(size_t)node * F + f] = dh_acc;
    float* dvp = dv + (size_t)node * THREEF + 3 * f;
    dvp[0] = dv0;
    dvp[1] = dv1;
    dvp[2] = dv2;
}

extern "C" void kernel_launch(void* const* d_in, const int* in_sizes, int n_in,
                              void* d_out, int out_size, void* d_ws, size_t ws_size,
                              hipStream_t stream) {
    const float* h_i    = (const float*)d_in[0];
    const float* v_i    = (const float*)d_in[1];
    const float* d_ij   = (const float*)d_in[2];
    const float* unit_r = (const float*)d_in[3];
    const int*   nbrs   = (const int*)  d_in[4];
    const float* W1     = (const float*)d_in[5];
    const float* b1     = (const float*)d_in[6];
    const float* W2     = (const float*)d_in[7];
    const float* b2     = (const float*)d_in[8];
    const float* Wr     = (const float*)d_in[9];
    const float* br     = (const float*)d_in[10];

    const int N = in_sizes[0] / F;       // 20000
    const int E = in_sizes[2];           // 320000

    float* dh = (float*)d_out;              // (N,128)
    float* dv = dh + (size_t)N * F;         // (N,128,3)

    // workspace: phi4 (4NF, interleaved) | pack (N*CAP*8) | WrT | cnt | W1T | W2T
    float*  phi  = (float*)d_ws;                           // 41 MB
    float*  pack = phi + (size_t)4 * N * F;                // 41 MB
    float*  WrT  = pack + (size_t)N * CAP * 8;             // 30 KB
    int*    cnt  = (int*)(WrT + 5 * 3 * 128 * 4);          // 80 KB
    __bf16* W1T  = (__bf16*)(cnt + N);                     // 32 KB
    __bf16* W2T  = W1T + 128 * 128;                        // 96 KB

    const int EB = (E + 255) / 256;      // 1250 build blocks

    hipMemsetAsync(cnt, 0, (size_t)N * sizeof(int), stream);

    prep_kernel<<<EB + 256 + 8, 256, 0, stream>>>(
        d_ij, unit_r, nbrs, W1, W2, Wr, cnt, pack, W1T, W2T, WrT, E, EB);
    mlp_mfma_kernel<<<(N + 63) / 64, 256, 0, stream>>>(h_i, W1T, b1, W2T, b2,
                                                       phi, N);
    gather_kernel<<<N / 2, 256, 0, stream>>>((const float4*)phi, v_i, WrT, br,
                                             cnt, pack, dh, dv, N);
}

// Round 6
// 290.269 us; speedup vs baseline: 2.5335x; 1.1253x over previous
//
#include <hip/hip_runtime.h>
#include <math.h>

#define F 128
#define THREEF 384
#define N_RBF 20
#define CUTOFF 5.0f
#define CAP 64
#define TLDS_STRIDE 136   // shorts; 272 B row: 16B-aligned, ~2-way banks (free)

typedef __bf16 bf16x8 __attribute__((ext_vector_type(8)));
typedef float  f32x4  __attribute__((ext_vector_type(4)));

// ---------------------------------------------------------------------------
// Prep (fused, block-range sliced):
//   blocks [0, EB)        : build — CSR slot via atomic, pack written directly
//                           at (dst,slot) so gather reads contiguously
//   blocks [EB, EB+256)   : wcast — W1,W2 -> bf16 k-major
//   blocks [EB+256, +8)   : wrt — chunked transpose of Wr for gather
// pack row = {s1, 2cos(x), fcut, ux, uy, uz, src_bits, 0}
// ---------------------------------------------------------------------------
__global__ __launch_bounds__(256) void prep_kernel(
    const float* __restrict__ d_ij, const float* __restrict__ unit_r,
    const int* __restrict__ nbrs,
    const float* __restrict__ W1, const float* __restrict__ W2,
    const float* __restrict__ Wr,
    int* __restrict__ cnt, float* __restrict__ pack,
    __bf16* __restrict__ W1T, __bf16* __restrict__ W2T,
    float* __restrict__ WrT, int E, int EB)
{
    const int tid = threadIdx.x;
    const int b   = blockIdx.x;

    if (b < EB) {                       // ---- build
        const int e = b * 256 + tid;
        if (e >= E) return;
        const int2 nb = ((const int2*)nbrs)[e];
        const int dst = nb.x;
        const int src = nb.y;
        const int slot = atomicAdd(&cnt[dst], 1);
        if (slot >= CAP) return;

        const float d = d_ij[e];
        const float x = (float)M_PI * d * (1.0f / CUTOFF);
        float sx, cx;
        __sincosf(x, &sx, &cx);
        const float fcut = (d < CUTOFF) ? 0.5f * (cx + 1.0f) : 0.0f;
        float4 q0, q1;
        q0.x = sx * fcut / d;           // rbff_1; recurrence keeps fcut/d scale
        q0.y = 2.0f * cx;
        q0.z = fcut;
        q0.w = unit_r[3 * e + 0];
        q1.x = unit_r[3 * e + 1];
        q1.y = unit_r[3 * e + 2];
        q1.z = __int_as_float(src);
        q1.w = 0.0f;
        float4* pk = (float4*)(pack + ((size_t)dst * CAP + slot) * 8);
        pk[0] = q0;
        pk[1] = q1;
    } else if (b < EB + 256) {          // ---- wcast
        const int idx = (b - EB) * 256 + tid;
        if (idx < 128 * 128) {
            const int n = idx >> 7, k = idx & 127;
            W1T[idx] = (__bf16)W1[k * F + n];
        }
        if (idx < 384 * 128) {
            const int n = idx >> 7, k = idx & 127;
            W2T[idx] = (__bf16)W2[k * THREEF + n];
        }
    } else {                            // ---- wrt
        const int idx = (b - EB - 256) * 256 + tid;   // 0..1919
        if (idx >= 5 * 3 * 128) return;
        const int f  = idx & 127;
        const int c  = (idx >> 7) % 3;
        const int n4 = idx / (3 * 128);
        float4 v;
        v.x = Wr[(4 * n4 + 0) * THREEF + c * 128 + f];
        v.y = Wr[(4 * n4 + 1) * THREEF + c * 128 + f];
        v.z = Wr[(4 * n4 + 2) * THREEF + c * 128 + f];
        v.w = Wr[(4 * n4 + 3) * THREEF + c * 128 + f];
        ((float4*)WrT)[idx] = v;
    }
}

// ---------------------------------------------------------------------------
// MLP via bf16 MFMA (fp32 accumulate): phi = silu(h@W1+b1)@W2 + b2,
// stored as 3 planes [c][node][f].
// R6: occupancy fix. Old: 313 blocks, each wave owned 16 nodes end-to-end
// -> 1250 waves total = 1.2 waves/SIMD, latency-exposed (both pipes idle).
// New: 1250 blocks; all 4 waves cooperate on the SAME 16 nodes. W1 phase:
// ct tiles 8 split 2/wave into shared t_lds[16][136]; one barrier; W2
// phase: ct tiles 24 split 6/wave. 4x waves, 4x less serial work per wave,
// same total MFMA.
// ---------------------------------------------------------------------------
__global__ __launch_bounds__(256) void mlp_mfma_kernel(
    const float* __restrict__ h,      // (N,128) fp32
    const __bf16* __restrict__ W1T,   // (128n,128k)
    const float* __restrict__ b1,     // (128)
    const __bf16* __restrict__ W2T,   // (384n,128k)
    const float* __restrict__ b2,     // (384)
    float* __restrict__ phi, int N)
{
    __shared__ __bf16 t_lds[16 * TLDS_STRIDE];   // (16 nodes, 128 feat) 4.3 KB

    const int wave = threadIdx.x >> 6;
    const int lane = threadIdx.x & 63;
    const int m    = lane & 15;
    const int quad = lane >> 4;
    const int node0 = blockIdx.x * 16;
    if (node0 >= N) return;

    bf16x8 a1[4];
    #pragma unroll
    for (int kb = 0; kb < 4; ++kb) {
        const float* hp = h + (size_t)(node0 + m) * F + kb * 32 + quad * 8;
        const float4 x0 = *(const float4*)hp;
        const float4 x1 = *(const float4*)(hp + 4);
        bf16x8 a;
        a[0] = (__bf16)x0.x; a[1] = (__bf16)x0.y;
        a[2] = (__bf16)x0.z; a[3] = (__bf16)x0.w;
        a[4] = (__bf16)x1.x; a[5] = (__bf16)x1.y;
        a[6] = (__bf16)x1.z; a[7] = (__bf16)x1.w;
        a1[kb] = a;
    }

    // W1 + silu: 8 ct tiles, 2 per wave, into shared t
    #pragma unroll
    for (int c2 = 0; c2 < 2; ++c2) {
        const int ct = wave * 2 + c2;
        f32x4 acc = {0.0f, 0.0f, 0.0f, 0.0f};
        #pragma unroll
        for (int kb = 0; kb < 4; ++kb) {
            const bf16x8 b =
                *(const bf16x8*)(W1T + (size_t)(ct * 16 + m) * F + kb * 32 + quad * 8);
            acc = __builtin_amdgcn_mfma_f32_16x16x32_bf16(a1[kb], b, acc, 0, 0, 0);
        }
        const int col = ct * 16 + m;
        const float bb = b1[col];
        #pragma unroll
        for (int reg = 0; reg < 4; ++reg) {
            const float x = acc[reg] + bb;
            const float s = x / (1.0f + __expf(-x));
            t_lds[(quad * 4 + reg) * TLDS_STRIDE + col] = (__bf16)s;
        }
    }
    __syncthreads();

    bf16x8 a2[4];
    #pragma unroll
    for (int kb = 0; kb < 4; ++kb)
        a2[kb] = *(const bf16x8*)&t_lds[m * TLDS_STRIDE + kb * 32 + quad * 8];

    // W2: 24 ct tiles, 6 per wave
    #pragma unroll
    for (int c6 = 0; c6 < 6; ++c6) {
        const int ct = c6 * 4 + wave;
        f32x4 acc = {0.0f, 0.0f, 0.0f, 0.0f};
        #pragma unroll
        for (int kb = 0; kb < 4; ++kb) {
            const bf16x8 b =
                *(const bf16x8*)(W2T + (size_t)(ct * 16 + m) * F + kb * 32 + quad * 8);
            acc = __builtin_amdgcn_mfma_f32_16x16x32_bf16(a2[kb], b, acc, 0, 0, 0);
        }
        const int col   = ct * 16 + m;
        const int plane = col >> 7;
        const int fc    = col & 127;
        const float bb  = b2[col];
        float* pp = phi + (size_t)plane * N * F + fc;
        #pragma unroll
        for (int reg = 0; reg < 4; ++reg) {
            const int row = quad * 4 + reg;
            pp[(size_t)(node0 + row) * F] = acc[reg] + bb;
        }
    }
}

// ---------------------------------------------------------------------------
// Gather: 256 threads = 2 nodes/block. EXACT R0 revert (verified 143-145 us,
// VALU 79%, occ 37%): per-node pack block staged into LDS once (coalesced
// float4); per-edge uniforms from LDS broadcast; WrT read per edge from VMEM
// (L1/L2-resident); planar phi. Five restructurings (w-in-LDS, w-pinned,
// s_rbf, phi4, 2/4-edge blocking) all lost: the backend allocates exactly
// 64 VGPRs for this loop shape and spills anything bigger.
// ---------------------------------------------------------------------------
__global__ __launch_bounds__(256) void gather_kernel(
    const float* __restrict__ phi,       // 3 planes of (N,128)
    const float* __restrict__ v_i,       // (N,128,3)
    const float* __restrict__ WrT,       // (5,3,128,4) chunked transpose
    const float* __restrict__ br,        // (384)
    const int*   __restrict__ cnt,       // (N)
    const float* __restrict__ pack,      // (N,CAP,8)
    float* __restrict__ dh,              // (N,128)
    float* __restrict__ dv,              // (N,128,3)
    int N)
{
    __shared__ float4 s_pack[2][CAP * 2];   // 4 KB

    const int tid  = threadIdx.x;
    const int half = tid >> 7;
    const int f    = tid & 127;
    const int node = blockIdx.x * 2 + half;

    const int deg0 = cnt[node];
    const int deg  = deg0 < CAP ? deg0 : CAP;

    {   // stage this node's pack rows: deg*2 float4s, coalesced
        const float4* src = (const float4*)(pack + (size_t)node * CAP * 8);
        if (f < 2 * deg) s_pack[half][f] = src[f];
    }
    __syncthreads();

    const float br0 = br[f], br1 = br[f + 128], br2 = br[f + 256];

    const float* phi0 = phi;
    const float* phi1 = phi + (size_t)N * F;
    const float* phi2 = phi + (size_t)2 * N * F;
    const float4* wT  = (const float4*)WrT;   // wT[(n4*3 + c)*128 + f]

    float dh_acc = 0.0f, dv0 = 0.0f, dv1 = 0.0f, dv2 = 0.0f;

    for (int i = 0; i < deg; ++i) {
        const float* q = (const float*)&s_pack[half][2 * i];
        const float s1   = q[0];
        const float twoc = q[1];
        const float fcut = q[2];
        const float ux   = q[3];
        const float uy   = q[4];
        const float uz   = q[5];
        // LDS value -> SGPR: only lgkmcnt wait, global-load queue stays full
        const int src = __builtin_amdgcn_readfirstlane(__float_as_int(q[6]));

        float a0 = br0 * fcut, a1 = br1 * fcut, a2 = br2 * fcut;
        float rp = 0.0f, rc = s1;
        #pragma unroll
        for (int n4 = 0; n4 < 5; ++n4) {
            const float4 w0 = wT[(n4 * 3 + 0) * 128 + f];
            const float4 w1 = wT[(n4 * 3 + 1) * 128 + f];
            const float4 w2 = wT[(n4 * 3 + 2) * 128 + f];
            #pragma unroll
            for (int k = 0; k < 4; ++k) {
                const float wa = ((const float*)&w0)[k];
                const float wb = ((const float*)&w1)[k];
                const float wc = ((const float*)&w2)[k];
                a0 = fmaf(rc, wa, a0);
                a1 = fmaf(rc, wb, a1);
                a2 = fmaf(rc, wc, a2);
                const float rn = fmaf(twoc, rc, -rp);
                rp = rc;
                rc = rn;
            }
        }

        const float f1 = phi0[(size_t)src * F + f] * a0;
        const float f2 = phi1[(size_t)src * F + f] * a1;
        const float f3 = phi2[(size_t)src * F + f] * a2;

        dh_acc += f3;

        const float* vs = v_i + (size_t)src * THREEF + 3 * f;
        dv0 = fmaf(f1, ux, fmaf(f2, vs[0], dv0));
        dv1 = fmaf(f1, uy, fmaf(f2, vs[1], dv1));
        dv2 = fmaf(f1, uz, fmaf(f2, vs[2], dv2));
    }

    dh[(size_t)node * F + f] = dh_acc;
    float* dvp = dv + (size_t)node * THREEF + 3 * f;
    dvp[0] = dv0;
    dvp[1] = dv1;
    dvp[2] = dv2;
}

extern "C" void kernel_launch(void* const* d_in, const int* in_sizes, int n_in,
                              void* d_out, int out_size, void* d_ws, size_t ws_size,
                              hipStream_t stream) {
    const float* h_i    = (const float*)d_in[0];
    const float* v_i    = (const float*)d_in[1];
    const float* d_ij   = (const float*)d_in[2];
    const float* unit_r = (const float*)d_in[3];
    const int*   nbrs   = (const int*)  d_in[4];
    const float* W1     = (const float*)d_in[5];
    const float* b1     = (const float*)d_in[6];
    const float* W2     = (const float*)d_in[7];
    const float* b2     = (const float*)d_in[8];
    const float* Wr     = (const float*)d_in[9];
    const float* br     = (const float*)d_in[10];

    const int N = in_sizes[0] / F;       // 20000
    const int E = in_sizes[2];           // 320000

    float* dh = (float*)d_out;              // (N,128)
    float* dv = dh + (size_t)N * F;         // (N,128,3)

    // workspace: phi (3NF) | pack (N*CAP*8) | WrT | cnt | W1T | W2T
    float*  phi  = (float*)d_ws;                           // 30.7 MB
    float*  pack = phi + (size_t)3 * N * F;                // 41 MB
    float*  WrT  = pack + (size_t)N * CAP * 8;             // 30 KB
    int*    cnt  = (int*)(WrT + 5 * 3 * 128 * 4);          // 80 KB
    __bf16* W1T  = (__bf16*)(cnt + N);                     // 32 KB
    __bf16* W2T  = W1T + 128 * 128;                        // 96 KB

    const int EB = (E + 255) / 256;      // 1250 build blocks

    hipMemsetAsync(cnt, 0, (size_t)N * sizeof(int), stream);

    prep_kernel<<<EB + 256 + 8, 256, 0, stream>>>(
        d_ij, unit_r, nbrs, W1, W2, Wr, cnt, pack, W1T, W2T, WrT, E, EB);
    mlp_mfma_kernel<<<(N + 15) / 16, 256, 0, stream>>>(h_i, W1T, b1, W2T, b2,
                                                       phi, N);
    gather_kernel<<<N / 2, 256, 0, stream>>>(phi, v_i, WrT, br, cnt, pack,
                                             dh, dv, N);
}